// Round 1
// 550.084 us; speedup vs baseline: 1.0216x; 1.0216x over previous
//
#include <hip/hip_runtime.h>
#include <hip/hip_bf16.h>

// ---------------- problem constants ----------------
#define NWIN 64      // windows per image (mask dim 0)

typedef __attribute__((ext_vector_type(8))) short v8s;   // 8 x bf16 raw bits (4 VGPRs)
typedef __attribute__((ext_vector_type(4))) float v4f;

// ---------------- workspace layout (bytes) ----------------
#define WQT_OFF   0u         // WqT  bf16 [256][256]  (out-major, contiguous in k)
#define WKVT_OFF  131072u    // WkvT bf16 [512][256]
#define WPT_OFF   393216u    // WpT  bf16 [256][256]
#define ITB_OFF   524288u    // float2 [8][64][64] = {inv_tau, cpb_bias}

static __device__ __forceinline__ short f2bf(float f) {
  union { float f; unsigned int u; } v; v.f = f;
  unsigned int u = v.u;
  return (short)((u + 0x7fffu + ((u >> 16) & 1u)) >> 16);   // RNE
}

// pack two fp32 -> one int holding (bf16(lo) | bf16(hi)<<16) via v_cvt_pk_bf16_f32
static __device__ __forceinline__ int packbf(float lo, float hi) {
  __hip_bfloat162 h = __float22bfloat162_rn(float2{lo, hi});
  union { __hip_bfloat162 h; int i; } u; u.h = h; return u.i;
}

// ---------------- prep: weight transpose+cast, inv_tau ----------------
__global__ void prep_kernel(const float* __restrict__ Wq, const float* __restrict__ Wkv,
                            const float* __restrict__ Wp, const float* __restrict__ tau,
                            short* __restrict__ WqT, short* __restrict__ WkvT,
                            short* __restrict__ WpT, float2* __restrict__ itb) {
  int id = blockIdx.x * 256 + threadIdx.x;
  if (id < 65536) {                       // WqT[o][i] = Wq[i][o]
    int o = id >> 8, i = id & 255;
    WqT[id] = f2bf(Wq[i * 256 + o]);
  } else if (id < 196608) {               // WkvT[o][i] = Wkv[i][o]
    int t = id - 65536; int o = t >> 8, i = t & 255;
    WkvT[t] = f2bf(Wkv[i * 512 + o]);
  } else if (id < 262144) {               // WpT[o][i] = Wp[i][o]
    int t = id - 196608; int o = t >> 8, i = t & 255;
    WpT[t] = f2bf(Wp[i * 256 + o]);
  } else if (id < 294912) {               // inv_tau
    int t = id - 262144;
    itb[t].x = 1.0f / fmaxf(tau[t], 0.01f);
  }
}

// ---------------- prep: continuous relative position bias MLP ----------------
__global__ void cpb_kernel(const float* __restrict__ w1, const float* __restrict__ b1,
                           const float* __restrict__ w2, const float* __restrict__ b2,
                           const float* __restrict__ lri, float2* __restrict__ itb) {
  int ij = blockIdx.x * 256 + threadIdx.x;     // 0..4095 = i*64+j
  float l0 = lri[ij * 2], l1 = lri[ij * 2 + 1];
  float acc[8];
#pragma unroll
  for (int h = 0; h < 8; ++h) acc[h] = b2[h];
  for (int c = 0; c < 256; ++c) {
    float hv = fmaxf(l0 * w1[c] + l1 * w1[256 + c] + b1[c], 0.0f);
#pragma unroll
    for (int h = 0; h < 8; ++h) acc[h] += hv * w2[c * 8 + h];
  }
#pragma unroll
  for (int h = 0; h < 8; ++h) itb[h * 4096 + ij].y = acc[h];
}

// ---------------- register transform: ᵀ-C-layout -> MFMA A/B fragment ----------------
// Source (per 16-wide tile): lane (cc,qd_s) holds pack u = (elem d=..+2u, d=..+2u+1),
// register-version p0* for tile-half 0, p1* for tile-half 1 (selected by qd>>1).
// Output: v8s fragment, word t from srcLane = cc + 32*(qd&1) + 16*(t>>1), u = t&1.
// (identity: md*16 + qd_s*4 + 2*(t&1) == 8*qd + 2*t)
static __device__ __forceinline__ v8s xform_tile(int p0a, int p0b, int p1a, int p1b,
                                                 int base, int mdsel) {
  int a0 = __shfl(p0a, base, 64),      b0 = __shfl(p1a, base, 64);
  int a1 = __shfl(p0b, base, 64),      b1 = __shfl(p1b, base, 64);
  int a2 = __shfl(p0a, base + 16, 64), b2 = __shfl(p1a, base + 16, 64);
  int a3 = __shfl(p0b, base + 16, 64), b3 = __shfl(p1b, base + 16, 64);
  union { v8s v; int i[4]; } r;
  r.i[0] = mdsel ? b0 : a0;
  r.i[1] = mdsel ? b1 : a1;
  r.i[2] = mdsel ? b2 : a2;
  r.i[3] = mdsel ? b3 : a3;
  return r.v;
}

// ---------------- main fused kernel: one block = one window, wave w = head w ----------------
// LDS: xs[64][264] bf16 @0 (reused for os), kvs[64][264] @16896 (reused for P-scratch).
// Total 67584 B -> 2 blocks/CU.
__global__ __launch_bounds__(512, 4) void wattn_kernel(
    const float* __restrict__ x, const float* __restrict__ KV,
    const float* __restrict__ mask,
    const float* __restrict__ bq, const float* __restrict__ bkv,
    const float* __restrict__ bp,
    const short* __restrict__ WqT, const short* __restrict__ WkvT,
    const short* __restrict__ WpT, const float2* __restrict__ itb,
    float* __restrict__ out) {
  __shared__ short sm[33792];

  const int b = blockIdx.x;
  const int tid = threadIdx.x;
  const int w = tid >> 6;          // wave index == head index
  const int lane = tid & 63;
  const int cc = lane & 15;
  const int qd = lane >> 4;
  const int base = cc + 32 * (qd & 1);
  const int mdsel = qd >> 1;
  const v4f vzero = {0.f, 0.f, 0.f, 0.f};
  short* xs = sm;
  short* kvs = sm + 16896;

  // ---- phase 0: stage x, KV -> bf16 LDS [64][264] (batched: 8 loads in flight) ----
  {
    const float4* xb = (const float4*)(x + (size_t)b * 16384);
    const float4* kb = (const float4*)(KV + (size_t)b * 16384);
#pragma unroll
    for (int half = 0; half < 2; ++half) {
      float4 vx[4], vk[4];
#pragma unroll
      for (int ii = 0; ii < 4; ++ii) {
        int i = tid + (half * 4 + ii) * 512;
        vx[ii] = xb[i];
        vk[ii] = kb[i];
      }
#pragma unroll
      for (int ii = 0; ii < 4; ++ii) {
        int i = tid + (half * 4 + ii) * 512;
        int r = i >> 6, col = (i & 63) << 2;
        int2 px = { packbf(vx[ii].x, vx[ii].y), packbf(vx[ii].z, vx[ii].w) };
        int2 pk = { packbf(vk[ii].x, vk[ii].y), packbf(vk[ii].z, vk[ii].w) };
        *(int2*)&xs[r * 264 + col] = px;
        *(int2*)&kvs[r * 264 + col] = pk;
      }
    }
  }
  // hoist first half of Wq fragments above the barrier: they arrive while we wait
  const short* wqb = WqT + (32 * w + cc) * 256 + qd * 8;
  v8s wq0[4], wq1[4];
#pragma unroll
  for (int it = 0; it < 4; ++it) {
    wq0[it] = *(const v8s*)(wqb + it * 32);
    wq1[it] = *(const v8s*)(wqb + 16 * 256 + it * 32);
  }
  __syncthreads();

  // ---- phase 1: q̂ᵀ = (Wq-slice)ᵀ x ᵀ (swapped operands) ----
  // Dq[md][nt]: lane holds q̂ᵀ[d = md*16+qd*4+rg][token = nt*16+cc]
  v4f Dq[2][4];
#pragma unroll
  for (int md = 0; md < 2; ++md)
#pragma unroll
    for (int nt = 0; nt < 4; ++nt) Dq[md][nt] = vzero;
  {
#pragma unroll
    for (int it = 0; it < 4; ++it) {      // hoisted-weight half
#pragma unroll
      for (int nt = 0; nt < 4; ++nt) {
        v8s bx = *(const v8s*)(xs + (nt * 16 + cc) * 264 + it * 32 + qd * 8);
        Dq[0][nt] = __builtin_amdgcn_mfma_f32_16x16x32_bf16(wq0[it], bx, Dq[0][nt], 0, 0, 0);
        Dq[1][nt] = __builtin_amdgcn_mfma_f32_16x16x32_bf16(wq1[it], bx, Dq[1][nt], 0, 0, 0);
      }
    }
#pragma unroll
    for (int it = 4; it < 8; ++it) {      // in-loop half
      v8s a0 = *(const v8s*)(wqb + it * 32);
      v8s a1 = *(const v8s*)(wqb + 16 * 256 + it * 32);
#pragma unroll
      for (int nt = 0; nt < 4; ++nt) {
        v8s bx = *(const v8s*)(xs + (nt * 16 + cc) * 264 + it * 32 + qd * 8);
        Dq[0][nt] = __builtin_amdgcn_mfma_f32_16x16x32_bf16(a0, bx, Dq[0][nt], 0, 0, 0);
        Dq[1][nt] = __builtin_amdgcn_mfma_f32_16x16x32_bf16(a1, bx, Dq[1][nt], 0, 0, 0);
      }
    }
  }
  // bias + per-head row-normalize + pack + xform -> qB (B-frags for Sᵀ)
  v8s qB[4];
  {
    v4f b0 = *(const v4f*)(bq + 32 * w + qd * 4);
    v4f b1 = *(const v4f*)(bq + 32 * w + 16 + qd * 4);
#pragma unroll
    for (int nt = 0; nt < 4; ++nt) {
      float s = 0.f;
#pragma unroll
      for (int rg = 0; rg < 4; ++rg) {
        float v0 = Dq[0][nt][rg] + b0[rg];
        float v1 = Dq[1][nt][rg] + b1[rg];
        Dq[0][nt][rg] = v0; Dq[1][nt][rg] = v1;
        s += v0 * v0 + v1 * v1;
      }
      s += __shfl_xor(s, 16); s += __shfl_xor(s, 32);
      float inv = rsqrtf(s + 1e-24f);
      int p00 = packbf(Dq[0][nt][0] * inv, Dq[0][nt][1] * inv);
      int p01 = packbf(Dq[0][nt][2] * inv, Dq[0][nt][3] * inv);
      int p10 = packbf(Dq[1][nt][0] * inv, Dq[1][nt][1] * inv);
      int p11 = packbf(Dq[1][nt][2] * inv, Dq[1][nt][3] * inv);
      qB[nt] = xform_tile(p00, p01, p10, p11, base, mdsel);
    }
  }

  // ---- phase 2: merged k (swapped) + v (normal) projection ----
  // Dk[md][nt]: k̂ᵀ[d][token] ; Dv[vt][dt]: v[token = vt*16+qd*4+rg][d = dt*16+cc]
  v4f Dk[2][4], Dv[4][2];
#pragma unroll
  for (int nt = 0; nt < 4; ++nt) {
    Dk[0][nt] = vzero; Dk[1][nt] = vzero;
    Dv[nt][0] = vzero; Dv[nt][1] = vzero;
  }
  {
    const short* wkb = WkvT + (32 * w + cc) * 256 + qd * 8;
    const short* wvb = WkvT + (256 + 32 * w + cc) * 256 + qd * 8;
#pragma unroll
    for (int it = 0; it < 8; ++it) {
      v8s ak0 = *(const v8s*)(wkb + it * 32);
      v8s ak1 = *(const v8s*)(wkb + 16 * 256 + it * 32);
      v8s bv0 = *(const v8s*)(wvb + it * 32);
      v8s bv1 = *(const v8s*)(wvb + 16 * 256 + it * 32);
#pragma unroll
      for (int nt = 0; nt < 4; ++nt) {
        v8s kf = *(const v8s*)(kvs + (nt * 16 + cc) * 264 + it * 32 + qd * 8);
        Dk[0][nt] = __builtin_amdgcn_mfma_f32_16x16x32_bf16(ak0, kf, Dk[0][nt], 0, 0, 0);
        Dk[1][nt] = __builtin_amdgcn_mfma_f32_16x16x32_bf16(ak1, kf, Dk[1][nt], 0, 0, 0);
        Dv[nt][0] = __builtin_amdgcn_mfma_f32_16x16x32_bf16(kf, bv0, Dv[nt][0], 0, 0, 0);
        Dv[nt][1] = __builtin_amdgcn_mfma_f32_16x16x32_bf16(kf, bv1, Dv[nt][1], 0, 0, 0);
      }
    }
  }
  // k: bias + normalize + xform -> kA (A-frags for Sᵀ)
  v8s kA[4];
  {
    v4f b0 = *(const v4f*)(bkv + 32 * w + qd * 4);
    v4f b1 = *(const v4f*)(bkv + 32 * w + 16 + qd * 4);
#pragma unroll
    for (int nt = 0; nt < 4; ++nt) {
      float s = 0.f;
#pragma unroll
      for (int rg = 0; rg < 4; ++rg) {
        float v0 = Dk[0][nt][rg] + b0[rg];
        float v1 = Dk[1][nt][rg] + b1[rg];
        Dk[0][nt][rg] = v0; Dk[1][nt][rg] = v1;
        s += v0 * v0 + v1 * v1;
      }
      s += __shfl_xor(s, 16); s += __shfl_xor(s, 32);
      float inv = rsqrtf(s + 1e-24f);
      int p00 = packbf(Dk[0][nt][0] * inv, Dk[0][nt][1] * inv);
      int p01 = packbf(Dk[0][nt][2] * inv, Dk[0][nt][3] * inv);
      int p10 = packbf(Dk[1][nt][0] * inv, Dk[1][nt][1] * inv);
      int p11 = packbf(Dk[1][nt][2] * inv, Dk[1][nt][3] * inv);
      kA[nt] = xform_tile(p00, p01, p10, p11, base, mdsel);
    }
  }
  // v: bias + pack + xform -> av[md][kc] (A-frags for PV: A[m=d][k=token])
  v8s av[2][2];
  {
    float bv0 = bkv[256 + 32 * w + cc];
    float bv1 = bkv[256 + 32 * w + 16 + cc];
    int Pv[4][2][2];
#pragma unroll
    for (int vt = 0; vt < 4; ++vt) {
      Pv[vt][0][0] = packbf(Dv[vt][0][0] + bv0, Dv[vt][0][1] + bv0);
      Pv[vt][0][1] = packbf(Dv[vt][0][2] + bv0, Dv[vt][0][3] + bv0);
      Pv[vt][1][0] = packbf(Dv[vt][1][0] + bv1, Dv[vt][1][1] + bv1);
      Pv[vt][1][1] = packbf(Dv[vt][1][2] + bv1, Dv[vt][1][3] + bv1);
    }
#pragma unroll
    for (int md = 0; md < 2; ++md)
#pragma unroll
      for (int kc = 0; kc < 2; ++kc)
        av[md][kc] = xform_tile(Pv[2 * kc][md][0], Pv[2 * kc][md][1],
                                Pv[2 * kc + 1][md][0], Pv[2 * kc + 1][md][1], base, mdsel);
  }

  // ---- phase 3: Sᵀ = k̂ q̂ᵀ (lane holds Sᵀ[j = jt*16+qd*4+rg][i = it*16+cc]) ----
  v4f Sv[4][4];
  __builtin_amdgcn_s_setprio(1);
#pragma unroll
  for (int jt = 0; jt < 4; ++jt)
#pragma unroll
    for (int it = 0; it < 4; ++it)
      Sv[jt][it] = __builtin_amdgcn_mfma_f32_16x16x32_bf16(kA[jt], qB[it], vzero, 0, 0, 0);
  __builtin_amdgcn_s_setprio(0);

  // ---- phase 4: scale/bias/mask + softmax over j (keys), loads batched ahead ----
  {
    const float4* itb4 = (const float4*)(itb + (size_t)w * 4096);
    const float4* mw4 = (const float4*)(mask + (size_t)(b & (NWIN - 1)) * 4096);
#pragma unroll
    for (int it = 0; it < 4; ++it) {
      int i = it * 16 + cc;
      float4 A[4], Bv[4], Mv[4];
#pragma unroll
      for (int jh = 0; jh < 2; ++jh) {
#pragma unroll
        for (int j2 = 0; j2 < 2; ++j2) {          // batch 6 float4 loads
          int jt = jh * 2 + j2;
          int e = i * 64 + jt * 16 + qd * 4;      // element index (i,j) base, float2 units
          A[jt] = itb4[e >> 1];
          Bv[jt] = itb4[(e >> 1) + 1];
          Mv[jt] = mw4[e >> 2];
        }
#pragma unroll
        for (int j2 = 0; j2 < 2; ++j2) {
          int jt = jh * 2 + j2;
          Sv[jt][it][0] = Sv[jt][it][0] * A[jt].x + A[jt].y + Mv[jt].x;
          Sv[jt][it][1] = Sv[jt][it][1] * A[jt].z + A[jt].w + Mv[jt].y;
          Sv[jt][it][2] = Sv[jt][it][2] * Bv[jt].x + Bv[jt].y + Mv[jt].z;
          Sv[jt][it][3] = Sv[jt][it][3] * Bv[jt].z + Bv[jt].w + Mv[jt].w;
        }
      }
      float mx = -3.4e38f;
#pragma unroll
      for (int jt = 0; jt < 4; ++jt)
#pragma unroll
        for (int rg = 0; rg < 4; ++rg) mx = fmaxf(mx, Sv[jt][it][rg]);
      mx = fmaxf(mx, __shfl_xor(mx, 16)); mx = fmaxf(mx, __shfl_xor(mx, 32));
      float sum = 0.f;
#pragma unroll
      for (int jt = 0; jt < 4; ++jt)
#pragma unroll
        for (int rg = 0; rg < 4; ++rg) {
          float ev = __expf(Sv[jt][it][rg] - mx);
          Sv[jt][it][rg] = ev;
          sum += ev;
        }
      sum += __shfl_xor(sum, 16); sum += __shfl_xor(sum, 32);
      float rs = 1.0f / sum;
#pragma unroll
      for (int jt = 0; jt < 4; ++jt)
#pragma unroll
        for (int rg = 0; rg < 4; ++rg) Sv[jt][it][rg] *= rs;
    }
  }

  // ---- phase 5: P -> LDS transpose (kvs region, per-wave swizzled slots) -> outᵀ ----
  // kvs is dead for ALL waves after this barrier (each wave only touches its own slot).
  __syncthreads();
  v4f Do[2][4];
  {
    char* psw = (char*)kvs + w * 4096;     // per-wave 4 KB (two 2 KB slots)
#pragma unroll
    for (int it = 0; it < 4; ++it) {
      char* ps = psw + (it & 1) * 2048;
      // write Pᵀ tile: lane holds P[j = jt*16+qd*4+rg][i = cc], layout [i][j] bf16,
      // byte ^= (i&7)<<4 swizzle (writes 2-way=free, b128 reads conflict-free)
#pragma unroll
      for (int jt = 0; jt < 4; ++jt) {
        int2 pr;
        pr.x = packbf(Sv[jt][it][0], Sv[jt][it][1]);
        pr.y = packbf(Sv[jt][it][2], Sv[jt][it][3]);
        int byte = (cc * 128 + jt * 32 + qd * 8) ^ ((cc & 7) << 4);
        *(int2*)(ps + byte) = pr;
      }
      // read B-frags: lane (cc,qd) reads j = f*32 + qd*8 .. +7 for col i = cc
      int rb0 = (cc * 128 + qd * 16) ^ ((cc & 7) << 4);
      int rb1 = (cc * 128 + 64 + qd * 16) ^ ((cc & 7) << 4);
      v8s pB0 = *(const v8s*)(ps + rb0);
      v8s pB1 = *(const v8s*)(ps + rb1);
      __builtin_amdgcn_s_setprio(1);
#pragma unroll
      for (int md = 0; md < 2; ++md) {
        v4f t = __builtin_amdgcn_mfma_f32_16x16x32_bf16(av[md][0], pB0, vzero, 0, 0, 0);
        Do[md][it] = __builtin_amdgcn_mfma_f32_16x16x32_bf16(av[md][1], pB1, t, 0, 0, 0);
      }
      __builtin_amdgcn_s_setprio(0);
    }
  }

  // ---- phase 6: gather heads into os[64][264] (@xs region), out = os @ Wp + bp ----
  // (pre-barrier removed: the phase-5 barrier already guarantees all waves are past
  //  phase 1 (xs reads) and phase 2 (kvs reads); os region = xs, P-scratch = kvs.)
#pragma unroll
  for (int md = 0; md < 2; ++md)
#pragma unroll
    for (int it = 0; it < 4; ++it) {
      int addr = (it * 16 + cc) * 264 + 32 * w + md * 16 + qd * 4;
      *(int*)&sm[addr] = packbf(Do[md][it][0], Do[md][it][1]);
      *(int*)&sm[addr + 2] = packbf(Do[md][it][2], Do[md][it][3]);
    }
  __syncthreads();

  v4f pa[4][2];
#pragma unroll
  for (int mt = 0; mt < 4; ++mt) { pa[mt][0] = vzero; pa[mt][1] = vzero; }
  {
    const short* wpb = WpT + (32 * w + cc) * 256 + qd * 8;
#pragma unroll
    for (int it = 0; it < 8; ++it) {
      v8s b0 = *(const v8s*)(wpb + it * 32);
      v8s b1 = *(const v8s*)(wpb + 16 * 256 + it * 32);
#pragma unroll
      for (int mt = 0; mt < 4; ++mt) {
        v8s a = *(const v8s*)(sm + (mt * 16 + cc) * 264 + it * 32 + qd * 8);
        pa[mt][0] = __builtin_amdgcn_mfma_f32_16x16x32_bf16(a, b0, pa[mt][0], 0, 0, 0);
        pa[mt][1] = __builtin_amdgcn_mfma_f32_16x16x32_bf16(a, b1, pa[mt][1], 0, 0, 0);
      }
    }
  }
  {
    float b0 = bp[32 * w + cc], b1 = bp[32 * w + 16 + cc];
    float* ob = out + (size_t)b * 16384;
#pragma unroll
    for (int mt = 0; mt < 4; ++mt)
#pragma unroll
      for (int rg = 0; rg < 4; ++rg) {
        int row = mt * 16 + qd * 4 + rg;
        ob[row * 256 + 32 * w + cc] = pa[mt][0][rg] + b0;
        ob[row * 256 + 32 * w + 16 + cc] = pa[mt][1][rg] + b1;
      }
  }
}

// ---------------- launch ----------------
extern "C" void kernel_launch(void* const* d_in, const int* in_sizes, int n_in,
                              void* d_out, int out_size, void* d_ws, size_t ws_size,
                              hipStream_t stream) {
  const float* x    = (const float*)d_in[0];
  const float* KV   = (const float*)d_in[1];
  const float* mask = (const float*)d_in[2];
  const float* Wq   = (const float*)d_in[3];
  const float* bq   = (const float*)d_in[4];
  const float* Wkv  = (const float*)d_in[5];
  const float* bkv  = (const float*)d_in[6];
  const float* Wp   = (const float*)d_in[7];
  const float* bp   = (const float*)d_in[8];
  const float* cw1  = (const float*)d_in[9];
  const float* cb1  = (const float*)d_in[10];
  const float* cw2  = (const float*)d_in[11];
  const float* cb2  = (const float*)d_in[12];
  const float* tau  = (const float*)d_in[13];
  const float* lri  = (const float*)d_in[14];

  unsigned char* ws = (unsigned char*)d_ws;
  short* WqT   = (short*)(ws + WQT_OFF);
  short* WkvT  = (short*)(ws + WKVT_OFF);
  short* WpT   = (short*)(ws + WPT_OFF);
  float2* itb  = (float2*)(ws + ITB_OFF);

  prep_kernel<<<1152, 256, 0, stream>>>(Wq, Wkv, Wp, tau, WqT, WkvT, WpT, itb);
  cpb_kernel<<<16, 256, 0, stream>>>(cw1, cb1, cw2, cb2, lri, itb);
  wattn_kernel<<<2048, 512, 0, stream>>>(x, KV, mask, bq, bkv, bp,
                                         WqT, WkvT, WpT, itb, (float*)d_out);
}

// Round 2
// 507.736 us; speedup vs baseline: 1.1068x; 1.0834x over previous
//
#include <hip/hip_runtime.h>
#include <hip/hip_bf16.h>

// ---------------- problem constants ----------------
#define NWIN 64      // windows per image (mask dim 0)

typedef __attribute__((ext_vector_type(8))) short v8s;   // 8 x bf16 raw bits (4 VGPRs)
typedef __attribute__((ext_vector_type(4))) float v4f;

// ---------------- workspace layout (bytes) ----------------
#define WQT_OFF   0u         // WqT  bf16 [256][256]  (out-major, contiguous in k)
#define WKVT_OFF  131072u    // WkvT bf16 [512][256]
#define WPT_OFF   393216u    // WpT  bf16 [256][256]
#define ITB_OFF   524288u    // uint [8][64][64] = (bf16 inv_tau | bf16 cpb_bias << 16)

static __device__ __forceinline__ short f2bf(float f) {
  union { float f; unsigned int u; } v; v.f = f;
  unsigned int u = v.u;
  return (short)((u + 0x7fffu + ((u >> 16) & 1u)) >> 16);   // RNE
}

// pack two fp32 -> one int holding (bf16(lo) | bf16(hi)<<16) via v_cvt_pk_bf16_f32
static __device__ __forceinline__ int packbf(float lo, float hi) {
  __hip_bfloat162 h = __float22bfloat162_rn(float2{lo, hi});
  union { __hip_bfloat162 h; int i; } u; u.h = h; return u.i;
}

// ---------------- prep: weight transpose+cast ----------------
__global__ void prep_kernel(const float* __restrict__ Wq, const float* __restrict__ Wkv,
                            const float* __restrict__ Wp,
                            short* __restrict__ WqT, short* __restrict__ WkvT,
                            short* __restrict__ WpT) {
  int id = blockIdx.x * 256 + threadIdx.x;
  if (id < 65536) {                       // WqT[o][i] = Wq[i][o]
    int o = id >> 8, i = id & 255;
    WqT[id] = f2bf(Wq[i * 256 + o]);
  } else if (id < 196608) {               // WkvT[o][i] = Wkv[i][o]
    int t = id - 65536; int o = t >> 8, i = t & 255;
    WkvT[t] = f2bf(Wkv[i * 512 + o]);
  } else if (id < 262144) {               // WpT[o][i] = Wp[i][o]
    int t = id - 196608; int o = t >> 8, i = t & 255;
    WpT[t] = f2bf(Wp[i * 256 + o]);
  }
}

// ---------------- prep: cpb MLP + packed bf16 (inv_tau, bias) table ----------------
__global__ void cpb_kernel(const float* __restrict__ w1, const float* __restrict__ b1,
                           const float* __restrict__ w2, const float* __restrict__ b2,
                           const float* __restrict__ lri, const float* __restrict__ tau,
                           unsigned int* __restrict__ itbh) {
  int ij = blockIdx.x * 256 + threadIdx.x;     // 0..4095 = i*64+j
  float l0 = lri[ij * 2], l1 = lri[ij * 2 + 1];
  float acc[8];
#pragma unroll
  for (int h = 0; h < 8; ++h) acc[h] = b2[h];
  for (int c = 0; c < 256; ++c) {
    float hv = fmaxf(l0 * w1[c] + l1 * w1[256 + c] + b1[c], 0.0f);
#pragma unroll
    for (int h = 0; h < 8; ++h) acc[h] += hv * w2[c * 8 + h];
  }
#pragma unroll
  for (int h = 0; h < 8; ++h) {
    float it = 1.0f / fmaxf(tau[h * 4096 + ij], 0.01f);
    itbh[h * 4096 + ij] = (unsigned int)packbf(it, acc[h]);   // lo=inv_tau, hi=bias
  }
}

// ---------------- register transform: ᵀ-C-layout -> MFMA A/B fragment ----------------
static __device__ __forceinline__ v8s xform_tile(int p0a, int p0b, int p1a, int p1b,
                                                 int base, int mdsel) {
  int a0 = __shfl(p0a, base, 64),      b0 = __shfl(p1a, base, 64);
  int a1 = __shfl(p0b, base, 64),      b1 = __shfl(p1b, base, 64);
  int a2 = __shfl(p0a, base + 16, 64), b2 = __shfl(p1a, base + 16, 64);
  int a3 = __shfl(p0b, base + 16, 64), b3 = __shfl(p1b, base + 16, 64);
  union { v8s v; int i[4]; } r;
  r.i[0] = mdsel ? b0 : a0;
  r.i[1] = mdsel ? b1 : a1;
  r.i[2] = mdsel ? b2 : a2;
  r.i[3] = mdsel ? b3 : a3;
  return r.v;
}

// ---------------- main fused kernel: one block = one window, wave w = head w ----------------
// LDS: xs[64][264] bf16 @0 (reused for os), kvs[64][264] @16896 (reused for P-scratch),
//      msk[64][64] bf16 @33792 (XOR-swizzled). Total 75776 B -> 2 blocks/CU.
__global__ __launch_bounds__(512, 4) void wattn_kernel(
    const float* __restrict__ x, const float* __restrict__ KV,
    const float* __restrict__ mask,
    const float* __restrict__ bq, const float* __restrict__ bkv,
    const float* __restrict__ bp,
    const short* __restrict__ WqT, const short* __restrict__ WkvT,
    const short* __restrict__ WpT, const unsigned int* __restrict__ itbh,
    float* __restrict__ out) {
  __shared__ short sm[37888];

  const int b = blockIdx.x;
  const int tid = threadIdx.x;
  const int w = tid >> 6;          // wave index == head index
  const int lane = tid & 63;
  const int cc = lane & 15;
  const int qd = lane >> 4;
  const int base = cc + 32 * (qd & 1);
  const int mdsel = qd >> 1;
  const v4f vzero = {0.f, 0.f, 0.f, 0.f};
  short* xs = sm;
  short* kvs = sm + 16896;
  short* ms = sm + 33792;

  // ---- phase 0: stage x, KV -> bf16 LDS [64][264]; mask -> bf16 LDS (swizzled) ----
  {
    const float4* xb = (const float4*)(x + (size_t)b * 16384);
    const float4* kb = (const float4*)(KV + (size_t)b * 16384);
    const float4* mb = (const float4*)(mask + (size_t)(b & (NWIN - 1)) * 4096);
    float4 m0 = mb[tid * 2], m1 = mb[tid * 2 + 1];
#pragma unroll
    for (int half = 0; half < 2; ++half) {
      float4 vx[4], vk[4];
#pragma unroll
      for (int ii = 0; ii < 4; ++ii) {
        int i = tid + (half * 4 + ii) * 512;
        vx[ii] = xb[i];
        vk[ii] = kb[i];
      }
#pragma unroll
      for (int ii = 0; ii < 4; ++ii) {
        int i = tid + (half * 4 + ii) * 512;
        int r = i >> 6, col = (i & 63) << 2;
        int2 px = { packbf(vx[ii].x, vx[ii].y), packbf(vx[ii].z, vx[ii].w) };
        int2 pk = { packbf(vk[ii].x, vk[ii].y), packbf(vk[ii].z, vk[ii].w) };
        *(int2*)&xs[r * 264 + col] = px;
        *(int2*)&kvs[r * 264 + col] = pk;
      }
    }
    // mask: thread t covers elements 8t..8t+7 (row i = t>>3); byte = 2e ^ ((i&7)<<3)
    int byte = (tid * 16) ^ (((tid >> 3) & 7) << 3);
    int2 p0 = { packbf(m0.x, m0.y), packbf(m0.z, m0.w) };
    int2 p1 = { packbf(m1.x, m1.y), packbf(m1.z, m1.w) };
    *(int2*)((char*)ms + byte) = p0;
    *(int2*)((char*)ms + (byte ^ 8)) = p1;
  }
  // hoist first half of Wq fragments above the barrier: they arrive while we wait
  const short* wqb = WqT + (32 * w + cc) * 256 + qd * 8;
  v8s wq0[4], wq1[4];
#pragma unroll
  for (int it = 0; it < 4; ++it) {
    wq0[it] = *(const v8s*)(wqb + it * 32);
    wq1[it] = *(const v8s*)(wqb + 16 * 256 + it * 32);
  }
  __syncthreads();

  // ---- phase 1: q̂ᵀ = (Wq-slice)ᵀ x ᵀ (swapped operands) ----
  v4f Dq[2][4];
#pragma unroll
  for (int md = 0; md < 2; ++md)
#pragma unroll
    for (int nt = 0; nt < 4; ++nt) Dq[md][nt] = vzero;
  {
#pragma unroll
    for (int it = 0; it < 4; ++it) {      // hoisted-weight half
#pragma unroll
      for (int nt = 0; nt < 4; ++nt) {
        v8s bx = *(const v8s*)(xs + (nt * 16 + cc) * 264 + it * 32 + qd * 8);
        Dq[0][nt] = __builtin_amdgcn_mfma_f32_16x16x32_bf16(wq0[it], bx, Dq[0][nt], 0, 0, 0);
        Dq[1][nt] = __builtin_amdgcn_mfma_f32_16x16x32_bf16(wq1[it], bx, Dq[1][nt], 0, 0, 0);
      }
    }
#pragma unroll
    for (int it = 4; it < 8; ++it) {      // in-loop half
      v8s a0 = *(const v8s*)(wqb + it * 32);
      v8s a1 = *(const v8s*)(wqb + 16 * 256 + it * 32);
#pragma unroll
      for (int nt = 0; nt < 4; ++nt) {
        v8s bx = *(const v8s*)(xs + (nt * 16 + cc) * 264 + it * 32 + qd * 8);
        Dq[0][nt] = __builtin_amdgcn_mfma_f32_16x16x32_bf16(a0, bx, Dq[0][nt], 0, 0, 0);
        Dq[1][nt] = __builtin_amdgcn_mfma_f32_16x16x32_bf16(a1, bx, Dq[1][nt], 0, 0, 0);
      }
    }
  }
  // bias + per-head row-normalize + pack + xform -> qB (B-frags for Sᵀ)
  v8s qB[4];
  {
    v4f b0 = *(const v4f*)(bq + 32 * w + qd * 4);
    v4f b1 = *(const v4f*)(bq + 32 * w + 16 + qd * 4);
#pragma unroll
    for (int nt = 0; nt < 4; ++nt) {
      float s = 0.f;
#pragma unroll
      for (int rg = 0; rg < 4; ++rg) {
        float v0 = Dq[0][nt][rg] + b0[rg];
        float v1 = Dq[1][nt][rg] + b1[rg];
        Dq[0][nt][rg] = v0; Dq[1][nt][rg] = v1;
        s += v0 * v0 + v1 * v1;
      }
      s += __shfl_xor(s, 16); s += __shfl_xor(s, 32);
      float inv = rsqrtf(s + 1e-24f);
      int p00 = packbf(Dq[0][nt][0] * inv, Dq[0][nt][1] * inv);
      int p01 = packbf(Dq[0][nt][2] * inv, Dq[0][nt][3] * inv);
      int p10 = packbf(Dq[1][nt][0] * inv, Dq[1][nt][1] * inv);
      int p11 = packbf(Dq[1][nt][2] * inv, Dq[1][nt][3] * inv);
      qB[nt] = xform_tile(p00, p01, p10, p11, base, mdsel);
    }
  }

  // ---- phase 2: merged k (swapped) + v (normal) projection ----
  v4f Dk[2][4], Dv[4][2];
#pragma unroll
  for (int nt = 0; nt < 4; ++nt) {
    Dk[0][nt] = vzero; Dk[1][nt] = vzero;
    Dv[nt][0] = vzero; Dv[nt][1] = vzero;
  }
  {
    const short* wkb = WkvT + (32 * w + cc) * 256 + qd * 8;
    const short* wvb = WkvT + (256 + 32 * w + cc) * 256 + qd * 8;
#pragma unroll
    for (int it = 0; it < 8; ++it) {
      v8s ak0 = *(const v8s*)(wkb + it * 32);
      v8s ak1 = *(const v8s*)(wkb + 16 * 256 + it * 32);
      v8s bv0 = *(const v8s*)(wvb + it * 32);
      v8s bv1 = *(const v8s*)(wvb + 16 * 256 + it * 32);
#pragma unroll
      for (int nt = 0; nt < 4; ++nt) {
        v8s kf = *(const v8s*)(kvs + (nt * 16 + cc) * 264 + it * 32 + qd * 8);
        Dk[0][nt] = __builtin_amdgcn_mfma_f32_16x16x32_bf16(ak0, kf, Dk[0][nt], 0, 0, 0);
        Dk[1][nt] = __builtin_amdgcn_mfma_f32_16x16x32_bf16(ak1, kf, Dk[1][nt], 0, 0, 0);
        Dv[nt][0] = __builtin_amdgcn_mfma_f32_16x16x32_bf16(kf, bv0, Dv[nt][0], 0, 0, 0);
        Dv[nt][1] = __builtin_amdgcn_mfma_f32_16x16x32_bf16(kf, bv1, Dv[nt][1], 0, 0, 0);
      }
    }
  }
  // k: bias + normalize + xform -> kA (A-frags for Sᵀ)
  v8s kA[4];
  {
    v4f b0 = *(const v4f*)(bkv + 32 * w + qd * 4);
    v4f b1 = *(const v4f*)(bkv + 32 * w + 16 + qd * 4);
#pragma unroll
    for (int nt = 0; nt < 4; ++nt) {
      float s = 0.f;
#pragma unroll
      for (int rg = 0; rg < 4; ++rg) {
        float v0 = Dk[0][nt][rg] + b0[rg];
        float v1 = Dk[1][nt][rg] + b1[rg];
        Dk[0][nt][rg] = v0; Dk[1][nt][rg] = v1;
        s += v0 * v0 + v1 * v1;
      }
      s += __shfl_xor(s, 16); s += __shfl_xor(s, 32);
      float inv = rsqrtf(s + 1e-24f);
      int p00 = packbf(Dk[0][nt][0] * inv, Dk[0][nt][1] * inv);
      int p01 = packbf(Dk[0][nt][2] * inv, Dk[0][nt][3] * inv);
      int p10 = packbf(Dk[1][nt][0] * inv, Dk[1][nt][1] * inv);
      int p11 = packbf(Dk[1][nt][2] * inv, Dk[1][nt][3] * inv);
      kA[nt] = xform_tile(p00, p01, p10, p11, base, mdsel);
    }
  }
  // v: bias + pack + xform -> av[md][kc] (A-frags for PV)
  v8s av[2][2];
  {
    float bv0 = bkv[256 + 32 * w + cc];
    float bv1 = bkv[256 + 32 * w + 16 + cc];
    int Pv[4][2][2];
#pragma unroll
    for (int vt = 0; vt < 4; ++vt) {
      Pv[vt][0][0] = packbf(Dv[vt][0][0] + bv0, Dv[vt][0][1] + bv0);
      Pv[vt][0][1] = packbf(Dv[vt][0][2] + bv0, Dv[vt][0][3] + bv0);
      Pv[vt][1][0] = packbf(Dv[vt][1][0] + bv1, Dv[vt][1][1] + bv1);
      Pv[vt][1][1] = packbf(Dv[vt][1][2] + bv1, Dv[vt][1][3] + bv1);
    }
#pragma unroll
    for (int md = 0; md < 2; ++md)
#pragma unroll
      for (int kc = 0; kc < 2; ++kc)
        av[md][kc] = xform_tile(Pv[2 * kc][md][0], Pv[2 * kc][md][1],
                                Pv[2 * kc + 1][md][0], Pv[2 * kc + 1][md][1], base, mdsel);
  }

  // ---- phase 3: Sᵀ = k̂ q̂ᵀ (lane holds Sᵀ[j = jt*16+qd*4+rg][i = it*16+cc]) ----
  v4f Sv[4][4];
  __builtin_amdgcn_s_setprio(1);
#pragma unroll
  for (int jt = 0; jt < 4; ++jt)
#pragma unroll
    for (int it = 0; it < 4; ++it)
      Sv[jt][it] = __builtin_amdgcn_mfma_f32_16x16x32_bf16(kA[jt], qB[it], vzero, 0, 0, 0);
  __builtin_amdgcn_s_setprio(0);

  // ---- phase 4: scale/bias/mask (packed bf16 tables) + softmax over j ----
  {
    const uint4* th4 = (const uint4*)(itbh + (size_t)w * 4096);
#pragma unroll
    for (int it = 0; it < 4; ++it) {
      int i = it * 16 + cc;
      uint4 T[4]; int2 M[4];
#pragma unroll
      for (int jt = 0; jt < 4; ++jt) {
        T[jt] = th4[(i * 64 + jt * 16 + qd * 4) >> 2];
        int byte = (i * 128 + jt * 32 + qd * 8) ^ ((i & 7) << 3);
        M[jt] = *(const int2*)((const char*)ms + byte);
      }
#pragma unroll
      for (int jt = 0; jt < 4; ++jt) {
        unsigned mxw = (unsigned)M[jt].x, myw = (unsigned)M[jt].y;
        float m0 = __uint_as_float(mxw << 16);
        float m1 = __uint_as_float(mxw & 0xffff0000u);
        float m2 = __uint_as_float(myw << 16);
        float m3 = __uint_as_float(myw & 0xffff0000u);
        unsigned u0 = T[jt].x, u1 = T[jt].y, u2 = T[jt].z, u3 = T[jt].w;
        Sv[jt][it][0] = Sv[jt][it][0] * __uint_as_float(u0 << 16) + (__uint_as_float(u0 & 0xffff0000u) + m0);
        Sv[jt][it][1] = Sv[jt][it][1] * __uint_as_float(u1 << 16) + (__uint_as_float(u1 & 0xffff0000u) + m1);
        Sv[jt][it][2] = Sv[jt][it][2] * __uint_as_float(u2 << 16) + (__uint_as_float(u2 & 0xffff0000u) + m2);
        Sv[jt][it][3] = Sv[jt][it][3] * __uint_as_float(u3 << 16) + (__uint_as_float(u3 & 0xffff0000u) + m3);
      }
      // tree max
      float mA = fmaxf(fmaxf(Sv[0][it][0], Sv[0][it][1]), fmaxf(Sv[0][it][2], Sv[0][it][3]));
      float mB = fmaxf(fmaxf(Sv[1][it][0], Sv[1][it][1]), fmaxf(Sv[1][it][2], Sv[1][it][3]));
      float mC = fmaxf(fmaxf(Sv[2][it][0], Sv[2][it][1]), fmaxf(Sv[2][it][2], Sv[2][it][3]));
      float mD = fmaxf(fmaxf(Sv[3][it][0], Sv[3][it][1]), fmaxf(Sv[3][it][2], Sv[3][it][3]));
      float mx = fmaxf(fmaxf(mA, mB), fmaxf(mC, mD));
      mx = fmaxf(mx, __shfl_xor(mx, 16)); mx = fmaxf(mx, __shfl_xor(mx, 32));
      // exp + tree sum
      float sj[4];
#pragma unroll
      for (int jt = 0; jt < 4; ++jt) {
        float e0 = __expf(Sv[jt][it][0] - mx);
        float e1 = __expf(Sv[jt][it][1] - mx);
        float e2 = __expf(Sv[jt][it][2] - mx);
        float e3 = __expf(Sv[jt][it][3] - mx);
        Sv[jt][it][0] = e0; Sv[jt][it][1] = e1;
        Sv[jt][it][2] = e2; Sv[jt][it][3] = e3;
        sj[jt] = (e0 + e1) + (e2 + e3);
      }
      float sum = (sj[0] + sj[1]) + (sj[2] + sj[3]);
      sum += __shfl_xor(sum, 16); sum += __shfl_xor(sum, 32);
      float rs = 1.0f / sum;
#pragma unroll
      for (int jt = 0; jt < 4; ++jt)
#pragma unroll
        for (int rg = 0; rg < 4; ++rg) Sv[jt][it][rg] *= rs;
    }
  }

  // ---- phase 5: P -> LDS transpose (kvs region, per-wave swizzled slots) -> outᵀ ----
  __syncthreads();
  v4f Do[2][4];
  {
    char* psw = (char*)kvs + w * 4096;     // per-wave 4 KB (two 2 KB slots)
#pragma unroll
    for (int it = 0; it < 4; ++it) {
      char* ps = psw + (it & 1) * 2048;
#pragma unroll
      for (int jt = 0; jt < 4; ++jt) {
        int2 pr;
        pr.x = packbf(Sv[jt][it][0], Sv[jt][it][1]);
        pr.y = packbf(Sv[jt][it][2], Sv[jt][it][3]);
        int byte = (cc * 128 + jt * 32 + qd * 8) ^ ((cc & 7) << 4);
        *(int2*)(ps + byte) = pr;
      }
      int rb0 = (cc * 128 + qd * 16) ^ ((cc & 7) << 4);
      int rb1 = (cc * 128 + 64 + qd * 16) ^ ((cc & 7) << 4);
      v8s pB0 = *(const v8s*)(ps + rb0);
      v8s pB1 = *(const v8s*)(ps + rb1);
      __builtin_amdgcn_s_setprio(1);
#pragma unroll
      for (int md = 0; md < 2; ++md) {
        v4f t = __builtin_amdgcn_mfma_f32_16x16x32_bf16(av[md][0], pB0, vzero, 0, 0, 0);
        Do[md][it] = __builtin_amdgcn_mfma_f32_16x16x32_bf16(av[md][1], pB1, t, 0, 0, 0);
      }
      __builtin_amdgcn_s_setprio(0);
    }
  }

  // hoist first two Wp fragment pairs: they arrive during gather + barrier wait
  const short* wpb = WpT + (32 * w + cc) * 256 + qd * 8;
  v8s wp0[2], wp1[2];
#pragma unroll
  for (int it = 0; it < 2; ++it) {
    wp0[it] = *(const v8s*)(wpb + it * 32);
    wp1[it] = *(const v8s*)(wpb + 16 * 256 + it * 32);
  }

  // ---- phase 6: gather heads into os[64][264] (@xs region), out = os @ Wp + bp ----
#pragma unroll
  for (int md = 0; md < 2; ++md)
#pragma unroll
    for (int it = 0; it < 4; ++it) {
      int addr = (it * 16 + cc) * 264 + 32 * w + md * 16 + qd * 4;
      *(int*)&sm[addr] = packbf(Do[md][it][0], Do[md][it][1]);
      *(int*)&sm[addr + 2] = packbf(Do[md][it][2], Do[md][it][3]);
    }
  __syncthreads();

  v4f pa[4][2];
#pragma unroll
  for (int mt = 0; mt < 4; ++mt) { pa[mt][0] = vzero; pa[mt][1] = vzero; }
  {
#pragma unroll
    for (int it = 0; it < 2; ++it) {      // hoisted-weight fragments
#pragma unroll
      for (int mt = 0; mt < 4; ++mt) {
        v8s a = *(const v8s*)(sm + (mt * 16 + cc) * 264 + it * 32 + qd * 8);
        pa[mt][0] = __builtin_amdgcn_mfma_f32_16x16x32_bf16(a, wp0[it], pa[mt][0], 0, 0, 0);
        pa[mt][1] = __builtin_amdgcn_mfma_f32_16x16x32_bf16(a, wp1[it], pa[mt][1], 0, 0, 0);
      }
    }
#pragma unroll
    for (int it = 2; it < 8; ++it) {
      v8s b0 = *(const v8s*)(wpb + it * 32);
      v8s b1 = *(const v8s*)(wpb + 16 * 256 + it * 32);
#pragma unroll
      for (int mt = 0; mt < 4; ++mt) {
        v8s a = *(const v8s*)(sm + (mt * 16 + cc) * 264 + it * 32 + qd * 8);
        pa[mt][0] = __builtin_amdgcn_mfma_f32_16x16x32_bf16(a, b0, pa[mt][0], 0, 0, 0);
        pa[mt][1] = __builtin_amdgcn_mfma_f32_16x16x32_bf16(a, b1, pa[mt][1], 0, 0, 0);
      }
    }
  }
  {
    float b0 = bp[32 * w + cc], b1 = bp[32 * w + 16 + cc];
    float* ob = out + (size_t)b * 16384;
#pragma unroll
    for (int mt = 0; mt < 4; ++mt)
#pragma unroll
      for (int rg = 0; rg < 4; ++rg) {
        int row = mt * 16 + qd * 4 + rg;
        ob[row * 256 + 32 * w + cc] = pa[mt][0][rg] + b0;
        ob[row * 256 + 32 * w + 16 + cc] = pa[mt][1][rg] + b1;
      }
  }
}

// ---------------- launch ----------------
extern "C" void kernel_launch(void* const* d_in, const int* in_sizes, int n_in,
                              void* d_out, int out_size, void* d_ws, size_t ws_size,
                              hipStream_t stream) {
  const float* x    = (const float*)d_in[0];
  const float* KV   = (const float*)d_in[1];
  const float* mask = (const float*)d_in[2];
  const float* Wq   = (const float*)d_in[3];
  const float* bq   = (const float*)d_in[4];
  const float* Wkv  = (const float*)d_in[5];
  const float* bkv  = (const float*)d_in[6];
  const float* Wp   = (const float*)d_in[7];
  const float* bp   = (const float*)d_in[8];
  const float* cw1  = (const float*)d_in[9];
  const float* cb1  = (const float*)d_in[10];
  const float* cw2  = (const float*)d_in[11];
  const float* cb2  = (const float*)d_in[12];
  const float* tau  = (const float*)d_in[13];
  const float* lri  = (const float*)d_in[14];

  unsigned char* ws = (unsigned char*)d_ws;
  short* WqT   = (short*)(ws + WQT_OFF);
  short* WkvT  = (short*)(ws + WKVT_OFF);
  short* WpT   = (short*)(ws + WPT_OFF);
  unsigned int* itbh = (unsigned int*)(ws + ITB_OFF);

  prep_kernel<<<1024, 256, 0, stream>>>(Wq, Wkv, Wp, WqT, WkvT, WpT);
  cpb_kernel<<<16, 256, 0, stream>>>(cw1, cb1, cw2, cb2, lri, tau, itbh);
  wattn_kernel<<<2048, 512, 0, stream>>>(x, KV, mask, bq, bkv, bp,
                                         WqT, WkvT, WpT, itbh, (float*)d_out);
}